// Round 5
// baseline (274.180 us; speedup 1.0000x reference)
//
#include <hip/hip_runtime.h>
#include <math.h>

#define NB 4
#define NN 4096
#define NC 512
#define NF 64

typedef __attribute__((ext_vector_type(8))) short short8;
typedef __attribute__((ext_vector_type(4))) float f32x4;

#define MFMA16(a,b,c) __builtin_amdgcn_mfma_f32_16x16x32_bf16(a,b,c,0,0,0)

static __device__ inline unsigned short f2bf(float f) {
    unsigned u = __float_as_uint(f);
    u = (u + 0x7FFFu + ((u >> 16) & 1u)) >> 16;
    return (unsigned short)u;
}
static __device__ inline float bf2f(unsigned short h) {
    return __uint_as_float(((unsigned)h) << 16);
}
static __device__ inline unsigned pkbf(float a, float b) {
    return (unsigned)f2bf(a) | ((unsigned)f2bf(b) << 16);
}
union U8 { unsigned short u[8]; short8 v; };

// ---------------------------------------------------------------------------
// Kernel 0: weight prep. wt_cat hi/lo [192][512] (rows = out-col, [th|ph|g]),
// wo_t [512][64] bf16. grid 128 x 256.
// ---------------------------------------------------------------------------
__global__ __launch_bounds__(256) void prep_kernel(
    const float* __restrict__ Wt, const float* __restrict__ Wp,
    const float* __restrict__ Wg, const float* __restrict__ Wo,
    unsigned short* __restrict__ wt_hi, unsigned short* __restrict__ wt_lo,
    unsigned short* __restrict__ wo_t)
{
    const int idx = blockIdx.x * 256 + threadIdx.x;
    if (blockIdx.x < 96) {
        const int c  = idx >> 7;            // 0..191
        const int k0 = (idx & 127) << 2;    // 0..508
        const float* W = (c < 64) ? Wt : (c < 128) ? Wp : Wg;
        const int cc = c & 63;
        #pragma unroll
        for (int j = 0; j < 4; ++j) {
            float v = W[(size_t)(k0 + j) * NF + cc];
            unsigned short h = f2bf(v);
            wt_hi[c * NC + k0 + j] = h;
            wt_lo[c * NC + k0 + j] = f2bf(v - bf2f(h));
        }
    } else {
        const int i2 = idx - 96 * 256;      // 0..8191
        const int c  = i2 >> 4;             // 0..511
        const int f0 = (i2 & 15) << 2;      // 0..60
        #pragma unroll
        for (int j = 0; j < 4; ++j)
            wo_t[c * NF + f0 + j] = f2bf(Wo[(size_t)(f0 + j) * NC + c]);
    }
}

// ---------------------------------------------------------------------------
// Kernel 1: projections via bf16x2-split MFMA. 32 rows/block, 256 thr (4 waves).
// wave w computes col frags {w, w+4, w+8} of [th(0..63)|ph|g] (16 cols each).
// theta/phi stored hi/lo [M][64]; g stored transposed gT[b][f][n] via LDS.
// ---------------------------------------------------------------------------
__global__ __launch_bounds__(256) void proj_kernel(
    const float* __restrict__ x,
    const unsigned short* __restrict__ wt_hi, const unsigned short* __restrict__ wt_lo,
    const float* __restrict__ bt, const float* __restrict__ bp, const float* __restrict__ bg,
    unsigned short* __restrict__ th_hi, unsigned short* __restrict__ th_lo,
    unsigned short* __restrict__ ph_hi, unsigned short* __restrict__ ph_lo,
    unsigned short* __restrict__ gT)
{
    __shared__ unsigned short gtr[4][32][16];
    const int tid  = threadIdx.x;
    const int wv   = tid >> 6;
    const int lane = tid & 63;
    const int l15  = lane & 15;
    const int g    = lane >> 4;
    const int row0 = blockIdx.x * 32;

    f32x4 acc[2][3];
    #pragma unroll
    for (int mi = 0; mi < 2; ++mi)
        #pragma unroll
        for (int nf = 0; nf < 3; ++nf) acc[mi][nf] = (f32x4){0.f,0.f,0.f,0.f};

    for (int k0 = 0; k0 < NC; k0 += 32) {
        short8 xhi[2], xlo[2];
        #pragma unroll
        for (int mi = 0; mi < 2; ++mi) {
            const float* xp = &x[(size_t)(row0 + 16*mi + l15) * NC + k0 + 8*g];
            float4 a = *reinterpret_cast<const float4*>(xp);
            float4 b = *reinterpret_cast<const float4*>(xp + 4);
            const float xv[8] = {a.x,a.y,a.z,a.w,b.x,b.y,b.z,b.w};
            U8 hh, ll;
            #pragma unroll
            for (int j = 0; j < 8; ++j) {
                hh.u[j] = f2bf(xv[j]);
                ll.u[j] = f2bf(xv[j] - bf2f(hh.u[j]));
            }
            xhi[mi] = hh.v; xlo[mi] = ll.v;
        }
        #pragma unroll
        for (int nf = 0; nf < 3; ++nf) {
            const int c = (wv + 4*nf) * 16 + l15;
            short8 wh = *reinterpret_cast<const short8*>(&wt_hi[(size_t)c * NC + k0 + 8*g]);
            short8 wl = *reinterpret_cast<const short8*>(&wt_lo[(size_t)c * NC + k0 + 8*g]);
            #pragma unroll
            for (int mi = 0; mi < 2; ++mi) {
                acc[mi][nf] = MFMA16(xhi[mi], wh, acc[mi][nf]);
                acc[mi][nf] = MFMA16(xlo[mi], wh, acc[mi][nf]);
                acc[mi][nf] = MFMA16(xhi[mi], wl, acc[mi][nf]);
            }
        }
    }

    // theta / phi epilogue: hi/lo split stores
    #pragma unroll
    for (int nf = 0; nf < 2; ++nf) {
        unsigned short* hi_arr = nf ? ph_hi : th_hi;
        unsigned short* lo_arr = nf ? ph_lo : th_lo;
        const float bb = (nf ? bp : bt)[wv*16 + l15];
        #pragma unroll
        for (int mi = 0; mi < 2; ++mi)
            #pragma unroll
            for (int reg = 0; reg < 4; ++reg) {
                const int m = row0 + 16*mi + 4*g + reg;
                float v = acc[mi][nf][reg] + bb;
                unsigned short h = f2bf(v);
                hi_arr[(size_t)m * NF + wv*16 + l15] = h;
                lo_arr[(size_t)m * NF + wv*16 + l15] = f2bf(v - bf2f(h));
            }
    }
    // g epilogue: per-wave LDS transpose -> coalesced gT stores
    {
        const float bb = bg[wv*16 + l15];
        #pragma unroll
        for (int mi = 0; mi < 2; ++mi)
            #pragma unroll
            for (int reg = 0; reg < 4; ++reg)
                gtr[wv][16*mi + 4*g + reg][l15] = f2bf(acc[mi][2][reg] + bb);
        asm volatile("s_waitcnt lgkmcnt(0)" ::: "memory");
        U8 pkt;
        #pragma unroll
        for (int j = 0; j < 8; ++j) pkt.u[j] = gtr[wv][8*g + j][l15];
        const int bbi = row0 >> 12;
        const int nbase = row0 & (NN - 1);
        *reinterpret_cast<short8*>(
            &gT[(size_t)(bbi*NF + wv*16 + l15) * NN + nbase + 8*g]) = pkt.v;
    }
}

// ---------------------------------------------------------------------------
// Kernel 2: flash attention. 512 thr = waves (p band of 32 rows x q in 0..3
// KV parity). Swapped QK^T (A=K, B=Q regs); packed in-reg P -> swizzled LDS;
// 4-way split-K merge. Dynamic LDS 128 KB: 4 tiles x (khi|klo|vT) + 8x4KB P.
// ---------------------------------------------------------------------------
__global__ __launch_bounds__(512, 1) void flash_kernel(
    const unsigned short* __restrict__ th_hi, const unsigned short* __restrict__ th_lo,
    const unsigned short* __restrict__ ph_hi, const unsigned short* __restrict__ ph_lo,
    const unsigned short* __restrict__ gT, unsigned short* __restrict__ attn)
{
    extern __shared__ __align__(16) char smem[];
    const int tid  = threadIdx.x;
    const int wv   = tid >> 6;
    const int lane = tid & 63;
    const int l15  = lane & 15;
    const int g    = lane >> 4;
    const int p    = wv & 1;       // 32-row band
    const int q    = wv >> 1;      // KV parity 0..3

    const int bid = blockIdx.y * 64 + blockIdx.x;
    const int wg  = (bid & 7) * 32 + (bid >> 3);   // XCD-chunked, bijective
    const int qt  = wg & 63;
    const int bb  = wg >> 6;
    const int row0 = qt * 64;
    const size_t base = (size_t)bb * NN * NF;

    // Q fragments in registers for the whole kernel
    short8 qhi[2][2], qlo[2][2];
    #pragma unroll
    for (int qf = 0; qf < 2; ++qf) {
        const size_t r = base + (size_t)(row0 + p*32 + qf*16 + l15) * NF;
        #pragma unroll
        for (int ks = 0; ks < 2; ++ks) {
            qhi[qf][ks] = *reinterpret_cast<const short8*>(&th_hi[r + ks*32 + 8*g]);
            qlo[qf][ks] = *reinterpret_cast<const short8*>(&th_lo[r + ks*32 + 8*g]);
        }
    }

    f32x4 o[2][4];
    #pragma unroll
    for (int qf = 0; qf < 2; ++qf)
        #pragma unroll
        for (int ff = 0; ff < 4; ++ff) o[qf][ff] = (f32x4){0.f,0.f,0.f,0.f};
    float m_run[2] = {-1e30f, -1e30f}, l_run[2] = {0.f, 0.f};

    const int r_st = tid >> 3;
    const int c_st = tid & 7;
    const int doff = r_st*128 + ((c_st*16) ^ ((r_st & 7) << 4));
    char* psb = smem + 98304 + wv * 4096;
    const int swzP = (l15 & 7) << 4;

    float4 pf[12];
#define LOADT(tt) { \
    const int j4 = 4*(tt); \
    _Pragma("unroll") \
    for (int s = 0; s < 4; ++s) { \
        const size_t kro = (base + (size_t)((j4+s)*64 + r_st) * NF) * 2 + c_st*16; \
        pf[s*3+0] = *reinterpret_cast<const float4*>((const char*)ph_hi + kro); \
        pf[s*3+1] = *reinterpret_cast<const float4*>((const char*)ph_lo + kro); \
        pf[s*3+2] = *reinterpret_cast<const float4*>((const char*)gT + \
            ((size_t)(bb*NF + r_st) * NN + (j4+s)*64) * 2 + c_st*16); \
    } }
#define WRITET() { \
    _Pragma("unroll") \
    for (int s = 0; s < 4; ++s) { \
        char* db = smem + s*24576; \
        *reinterpret_cast<float4*>(db + doff)         = pf[s*3+0]; \
        *reinterpret_cast<float4*>(db + 8192 + doff)  = pf[s*3+1]; \
        *reinterpret_cast<float4*>(db + 16384 + doff) = pf[s*3+2]; \
    } }

    LOADT(0);
    WRITET();
    __syncthreads();

    for (int t = 0; t < 16; ++t) {
        if (t < 15) LOADT(t + 1);

        const char* kb = smem + q * 24576;

        // ---- QK^T swapped: sacc[qf][mi][reg] = S[qrow=qf*16+l15][kv=mi*16+4g+reg]
        f32x4 sacc[2][4];
        #pragma unroll
        for (int qf = 0; qf < 2; ++qf)
            #pragma unroll
            for (int mi = 0; mi < 4; ++mi) sacc[qf][mi] = (f32x4){0.f,0.f,0.f,0.f};

        __builtin_amdgcn_s_setprio(1);
        #pragma unroll
        for (int ks = 0; ks < 2; ++ks) {
            short8 kh[4], kl[4];
            #pragma unroll
            for (int mi = 0; mi < 4; ++mi) {
                const int r = mi*16 + l15;
                const char* rp = kb + r*128;
                const int off = (ks*64 + g*16) ^ ((r & 7) << 4);
                kh[mi] = *reinterpret_cast<const short8*>(rp + off);
                kl[mi] = *reinterpret_cast<const short8*>(rp + 8192 + off);
            }
            #pragma unroll
            for (int qf = 0; qf < 2; ++qf)
                #pragma unroll
                for (int mi = 0; mi < 4; ++mi) {
                    sacc[qf][mi] = MFMA16(kh[mi], qhi[qf][ks], sacc[qf][mi]);
                    sacc[qf][mi] = MFMA16(kl[mi], qhi[qf][ks], sacc[qf][mi]);
                    sacc[qf][mi] = MFMA16(kh[mi], qlo[qf][ks], sacc[qf][mi]);
                }
        }
        __builtin_amdgcn_s_setprio(0);

        // ---- online softmax: one q-row per lane, kv spread over g (shfl 16,32)
        #pragma unroll
        for (int qf = 0; qf < 2; ++qf) {
            float mx = -1e30f;
            #pragma unroll
            for (int mi = 0; mi < 4; ++mi)
                #pragma unroll
                for (int reg = 0; reg < 4; ++reg) mx = fmaxf(mx, sacc[qf][mi][reg]);
            mx = fmaxf(mx, __shfl_xor(mx, 16));
            mx = fmaxf(mx, __shfl_xor(mx, 32));
            const float mnew = fmaxf(m_run[qf], mx);
            const float scl  = __expf(m_run[qf] - mnew);
            m_run[qf] = mnew;
            float ps = 0.f;
            uint2 w[4];
            #pragma unroll
            for (int mi = 0; mi < 4; ++mi) {
                float p0 = __expf(sacc[qf][mi][0] - mnew);
                float p1 = __expf(sacc[qf][mi][1] - mnew);
                float p2 = __expf(sacc[qf][mi][2] - mnew);
                float p3 = __expf(sacc[qf][mi][3] - mnew);
                ps += (p0 + p1) + (p2 + p3);
                w[mi].x = pkbf(p0, p1);
                w[mi].y = pkbf(p2, p3);
            }
            ps += __shfl_xor(ps, 16);
            ps += __shfl_xor(ps, 32);
            l_run[qf] = l_run[qf] * scl + ps;
            #pragma unroll
            for (int ff = 0; ff < 4; ++ff) o[qf][ff] *= scl;
            char* prow = psb + (qf*16 + l15) * 128;
            #pragma unroll
            for (int mi = 0; mi < 4; ++mi)
                *reinterpret_cast<uint2*>(prow + ((mi*32 + 8*g) ^ swzP)) = w[mi];
        }
        asm volatile("s_waitcnt lgkmcnt(0)" ::: "memory");
        __builtin_amdgcn_sched_barrier(0);

        // ---- PV: O^T = V^T * P^T (A = vT from LDS, B = P from LDS)
        __builtin_amdgcn_s_setprio(1);
        const char* vb = kb + 16384;
        #pragma unroll
        for (int ks = 0; ks < 2; ++ks) {
            short8 pb[2];
            #pragma unroll
            for (int qf = 0; qf < 2; ++qf)
                pb[qf] = *reinterpret_cast<const short8*>(
                    psb + (qf*16 + l15)*128 + ((ks*64 + g*16) ^ swzP));
            #pragma unroll
            for (int ff = 0; ff < 4; ++ff) {
                const int fr = ff*16 + l15;
                short8 va = *reinterpret_cast<const short8*>(
                    vb + fr*128 + ((ks*64 + g*16) ^ ((fr & 7) << 4)));
                o[0][ff] = MFMA16(va, pb[0], o[0][ff]);
                o[1][ff] = MFMA16(va, pb[1], o[1][ff]);
            }
        }
        __builtin_amdgcn_s_setprio(0);

        __syncthreads();
        if (t < 15) { WRITET(); __syncthreads(); }
    }

    // ---- 4-way split-K merge (reuses staging LDS)
    float* mO = (float*)smem;                   // 6 bufs x [32][64] f32
    float* ml = (float*)(smem + 49152);         // [64 rows][3][2]
    if (q > 0) {
        float* bo = mO + ((q - 1)*2 + p) * 2048;
        #pragma unroll
        for (int qf = 0; qf < 2; ++qf) {
            const int rb = qf*16 + l15;
            #pragma unroll
            for (int ff = 0; ff < 4; ++ff)
                *reinterpret_cast<f32x4*>(&bo[rb*64 + ff*16 + 4*g]) = o[qf][ff];
            if (g == 0) {
                const int rg = p*32 + qf*16 + l15;
                ml[rg*6 + (q-1)*2 + 0] = m_run[qf];
                ml[rg*6 + (q-1)*2 + 1] = l_run[qf];
            }
        }
    }
    __syncthreads();
    if (q == 0) {
        #pragma unroll
        for (int qf = 0; qf < 2; ++qf) {
            const int rg = p*32 + qf*16 + l15;
            float m = m_run[qf];
            float mi_[3], li_[3];
            #pragma unroll
            for (int i = 0; i < 3; ++i) {
                mi_[i] = ml[rg*6 + i*2 + 0];
                li_[i] = ml[rg*6 + i*2 + 1];
                m = fmaxf(m, mi_[i]);
            }
            const float a0 = __expf(m_run[qf] - m);
            float L = a0 * l_run[qf];
            float ai[3];
            #pragma unroll
            for (int i = 0; i < 3; ++i) { ai[i] = __expf(mi_[i] - m); L += ai[i]*li_[i]; }
            const float inv = 1.0f / L;
            #pragma unroll
            for (int ff = 0; ff < 4; ++ff) {
                f32x4 a = o[qf][ff] * a0;
                #pragma unroll
                for (int i = 0; i < 3; ++i) {
                    const float* bo = mO + (i*2 + p)*2048 + (qf*16 + l15)*64 + ff*16 + 4*g;
                    float4 v = *reinterpret_cast<const float4*>(bo);
                    a[0] += ai[i]*v.x; a[1] += ai[i]*v.y;
                    a[2] += ai[i]*v.z; a[3] += ai[i]*v.w;
                }
                ushort4 st;
                st.x = f2bf(a[0]*inv); st.y = f2bf(a[1]*inv);
                st.z = f2bf(a[2]*inv); st.w = f2bf(a[3]*inv);
                *reinterpret_cast<ushort4*>(
                    &attn[base + (size_t)(row0 + p*32 + qf*16 + l15)*NF + ff*16 + 4*g]) = st;
            }
        }
    }
#undef LOADT
#undef WRITET
}

// ---------------------------------------------------------------------------
// Kernel 3: out = x + attn(bf16) @ WoT(bf16) + b.  32 rows/block, 256 thr.
// wave w -> cols 128w..128w+127 (8 frags).
// ---------------------------------------------------------------------------
__global__ __launch_bounds__(256) void outproj_kernel(
    const unsigned short* __restrict__ attn, const unsigned short* __restrict__ wo_t,
    const float* __restrict__ bo, const float* __restrict__ x, float* __restrict__ out)
{
    const int tid  = threadIdx.x;
    const int wv   = tid >> 6;
    const int lane = tid & 63;
    const int l15  = lane & 15;
    const int g    = lane >> 4;
    const int row0 = blockIdx.x * 32;

    short8 af[2][2];
    #pragma unroll
    for (int mi = 0; mi < 2; ++mi)
        #pragma unroll
        for (int ks = 0; ks < 2; ++ks)
            af[mi][ks] = *reinterpret_cast<const short8*>(
                &attn[(size_t)(row0 + 16*mi + l15) * NF + ks*32 + 8*g]);

    f32x4 acc[2][8];
    #pragma unroll
    for (int mi = 0; mi < 2; ++mi)
        #pragma unroll
        for (int nf = 0; nf < 8; ++nf) acc[mi][nf] = (f32x4){0.f,0.f,0.f,0.f};

    #pragma unroll
    for (int nf = 0; nf < 8; ++nf) {
        const int c = wv*128 + nf*16 + l15;
        #pragma unroll
        for (int ks = 0; ks < 2; ++ks) {
            short8 wf = *reinterpret_cast<const short8*>(&wo_t[(size_t)c * NF + ks*32 + 8*g]);
            acc[0][nf] = MFMA16(af[0][ks], wf, acc[0][nf]);
            acc[1][nf] = MFMA16(af[1][ks], wf, acc[1][nf]);
        }
    }

    float bov[8];
    #pragma unroll
    for (int nf = 0; nf < 8; ++nf) bov[nf] = bo[wv*128 + nf*16 + l15];

    #pragma unroll
    for (int mi = 0; mi < 2; ++mi)
        #pragma unroll
        for (int reg = 0; reg < 4; ++reg) {
            const int m = row0 + 16*mi + 4*g + reg;
            #pragma unroll
            for (int nf = 0; nf < 8; ++nf) {
                const size_t idx = (size_t)m * NC + wv*128 + nf*16 + l15;
                out[idx] = acc[mi][nf][reg] + bov[nf] + x[idx];
            }
        }
}

// ---------------------------------------------------------------------------
extern "C" void kernel_launch(void* const* d_in, const int* in_sizes, int n_in,
                              void* d_out, int out_size, void* d_ws, size_t ws_size,
                              hipStream_t stream) {
    const float* x  = (const float*)d_in[0];
    const float* Wt = (const float*)d_in[1];
    const float* bt = (const float*)d_in[2];
    const float* Wp = (const float*)d_in[3];
    const float* bp = (const float*)d_in[4];
    const float* Wg = (const float*)d_in[5];
    const float* bg = (const float*)d_in[6];
    const float* Wo = (const float*)d_in[7];
    const float* bo = (const float*)d_in[8];
    float* out = (float*)d_out;

    const size_t per = (size_t)NB * NN * NF;   // 1,048,576
    unsigned short* th_hi = (unsigned short*)d_ws;
    unsigned short* th_lo = th_hi + per;
    unsigned short* ph_hi = th_lo + per;
    unsigned short* ph_lo = ph_hi + per;
    unsigned short* gTw   = ph_lo + per;
    unsigned short* at_bf = gTw + per;
    unsigned short* wt_hi = at_bf + per;
    unsigned short* wt_lo = wt_hi + 192 * NC;
    unsigned short* wo_t  = wt_lo + 192 * NC;

    hipFuncSetAttribute(reinterpret_cast<const void*>(flash_kernel),
                        hipFuncAttributeMaxDynamicSharedMemorySize, 131072);

    const int M = NB * NN;  // 16384

    prep_kernel<<<128, 256, 0, stream>>>(Wt, Wp, Wg, Wo, wt_hi, wt_lo, wo_t);
    proj_kernel<<<M / 32, 256, 0, stream>>>(
        x, wt_hi, wt_lo, bt, bp, bg, th_hi, th_lo, ph_hi, ph_lo, gTw);
    flash_kernel<<<dim3(64, 4), 512, 131072, stream>>>(
        th_hi, th_lo, ph_hi, ph_lo, gTw, at_bf);
    outproj_kernel<<<M / 32, 256, 0, stream>>>(at_bf, wo_t, bo, x, out);
}

// Round 6
// 203.231 us; speedup vs baseline: 1.3491x; 1.3491x over previous
//
#include <hip/hip_runtime.h>
#include <math.h>

#define NB 4
#define NN 4096
#define NC 512
#define NF 64

typedef __attribute__((ext_vector_type(8))) short short8;
typedef __attribute__((ext_vector_type(4))) float f32x4;

#define MFMA16(a,b,c) __builtin_amdgcn_mfma_f32_16x16x32_bf16(a,b,c,0,0,0)

static __device__ inline unsigned short f2bf(float f) {
    unsigned u = __float_as_uint(f);
    u = (u + 0x7FFFu + ((u >> 16) & 1u)) >> 16;
    return (unsigned short)u;
}
static __device__ inline float bf2f(unsigned short h) {
    return __uint_as_float(((unsigned)h) << 16);
}
static __device__ inline unsigned pkbf(float a, float b) {
    return (unsigned)f2bf(a) | ((unsigned)f2bf(b) << 16);
}
union U8 { unsigned short u[8]; short8 v; };

// global -> LDS async DMA, 16B per lane. LDS dest is wave-uniform base
// (+ lane*16 implicit); global src is per-lane.
static __device__ __forceinline__ void gload16(const void* gsrc, void* ldst) {
    __builtin_amdgcn_global_load_lds(
        (const __attribute__((address_space(1))) unsigned int*)gsrc,
        (__attribute__((address_space(3))) unsigned int*)ldst,
        16, 0, 0);
}

// ---------------------------------------------------------------------------
// Kernel 0: weight prep (unchanged).
// ---------------------------------------------------------------------------
__global__ __launch_bounds__(256) void prep_kernel(
    const float* __restrict__ Wt, const float* __restrict__ Wp,
    const float* __restrict__ Wg, const float* __restrict__ Wo,
    unsigned short* __restrict__ wt_hi, unsigned short* __restrict__ wt_lo,
    unsigned short* __restrict__ wo_t)
{
    const int idx = blockIdx.x * 256 + threadIdx.x;
    if (blockIdx.x < 96) {
        const int c  = idx >> 7;
        const int k0 = (idx & 127) << 2;
        const float* W = (c < 64) ? Wt : (c < 128) ? Wp : Wg;
        const int cc = c & 63;
        #pragma unroll
        for (int j = 0; j < 4; ++j) {
            float v = W[(size_t)(k0 + j) * NF + cc];
            unsigned short h = f2bf(v);
            wt_hi[c * NC + k0 + j] = h;
            wt_lo[c * NC + k0 + j] = f2bf(v - bf2f(h));
        }
    } else {
        const int i2 = idx - 96 * 256;
        const int c  = i2 >> 4;
        const int f0 = (i2 & 15) << 2;
        #pragma unroll
        for (int j = 0; j < 4; ++j)
            wo_t[c * NF + f0 + j] = f2bf(Wo[(size_t)(f0 + j) * NC + c]);
    }
}

// ---------------------------------------------------------------------------
// Kernel 1: projections via bf16x2-split MFMA (unchanged from round 5).
// ---------------------------------------------------------------------------
__global__ __launch_bounds__(256) void proj_kernel(
    const float* __restrict__ x,
    const unsigned short* __restrict__ wt_hi, const unsigned short* __restrict__ wt_lo,
    const float* __restrict__ bt, const float* __restrict__ bp, const float* __restrict__ bg,
    unsigned short* __restrict__ th_hi, unsigned short* __restrict__ th_lo,
    unsigned short* __restrict__ ph_hi, unsigned short* __restrict__ ph_lo,
    unsigned short* __restrict__ gT)
{
    __shared__ unsigned short gtr[4][32][16];
    const int tid  = threadIdx.x;
    const int wv   = tid >> 6;
    const int lane = tid & 63;
    const int l15  = lane & 15;
    const int g    = lane >> 4;
    const int row0 = blockIdx.x * 32;

    f32x4 acc[2][3];
    #pragma unroll
    for (int mi = 0; mi < 2; ++mi)
        #pragma unroll
        for (int nf = 0; nf < 3; ++nf) acc[mi][nf] = (f32x4){0.f,0.f,0.f,0.f};

    for (int k0 = 0; k0 < NC; k0 += 32) {
        short8 xhi[2], xlo[2];
        #pragma unroll
        for (int mi = 0; mi < 2; ++mi) {
            const float* xp = &x[(size_t)(row0 + 16*mi + l15) * NC + k0 + 8*g];
            float4 a = *reinterpret_cast<const float4*>(xp);
            float4 b = *reinterpret_cast<const float4*>(xp + 4);
            const float xv[8] = {a.x,a.y,a.z,a.w,b.x,b.y,b.z,b.w};
            U8 hh, ll;
            #pragma unroll
            for (int j = 0; j < 8; ++j) {
                hh.u[j] = f2bf(xv[j]);
                ll.u[j] = f2bf(xv[j] - bf2f(hh.u[j]));
            }
            xhi[mi] = hh.v; xlo[mi] = ll.v;
        }
        #pragma unroll
        for (int nf = 0; nf < 3; ++nf) {
            const int c = (wv + 4*nf) * 16 + l15;
            short8 wh = *reinterpret_cast<const short8*>(&wt_hi[(size_t)c * NC + k0 + 8*g]);
            short8 wl = *reinterpret_cast<const short8*>(&wt_lo[(size_t)c * NC + k0 + 8*g]);
            #pragma unroll
            for (int mi = 0; mi < 2; ++mi) {
                acc[mi][nf] = MFMA16(xhi[mi], wh, acc[mi][nf]);
                acc[mi][nf] = MFMA16(xlo[mi], wh, acc[mi][nf]);
                acc[mi][nf] = MFMA16(xhi[mi], wl, acc[mi][nf]);
            }
        }
    }

    #pragma unroll
    for (int nf = 0; nf < 2; ++nf) {
        unsigned short* hi_arr = nf ? ph_hi : th_hi;
        unsigned short* lo_arr = nf ? ph_lo : th_lo;
        const float bb = (nf ? bp : bt)[wv*16 + l15];
        #pragma unroll
        for (int mi = 0; mi < 2; ++mi)
            #pragma unroll
            for (int reg = 0; reg < 4; ++reg) {
                const int m = row0 + 16*mi + 4*g + reg;
                float v = acc[mi][nf][reg] + bb;
                unsigned short h = f2bf(v);
                hi_arr[(size_t)m * NF + wv*16 + l15] = h;
                lo_arr[(size_t)m * NF + wv*16 + l15] = f2bf(v - bf2f(h));
            }
    }
    {
        const float bb = bg[wv*16 + l15];
        #pragma unroll
        for (int mi = 0; mi < 2; ++mi)
            #pragma unroll
            for (int reg = 0; reg < 4; ++reg)
                gtr[wv][16*mi + 4*g + reg][l15] = f2bf(acc[mi][2][reg] + bb);
        asm volatile("s_waitcnt lgkmcnt(0)" ::: "memory");
        U8 pkt;
        #pragma unroll
        for (int j = 0; j < 8; ++j) pkt.u[j] = gtr[wv][8*g + j][l15];
        const int bbi = row0 >> 12;
        const int nbase = row0 & (NN - 1);
        *reinterpret_cast<short8*>(
            &gT[(size_t)(bbi*NF + wv*16 + l15) * NN + nbase + 8*g]) = pkt.v;
    }
}

// ---------------------------------------------------------------------------
// Kernel 2: flash attention v4. 512 thr; wave = (band pband 0..3 of 16 q-rows)
// x (KV parity q 0..1). Staging = global_load_lds (16B) direct to LDS with
// inverse-swizzled per-lane SOURCE (LDS dest linear) -> no staging registers.
// Double-buffered 2-tile sets; 1 barrier/iter; 2-way split-K merge.
// Dyn LDS 112KB: buf[d in 0,1] d*49152 + s*24576 + {khi 0, klo 8192, vT 16384};
// P at 98304 + wv*2048.
// ---------------------------------------------------------------------------
__global__ __launch_bounds__(512, 2) void flash_kernel(
    const unsigned short* __restrict__ th_hi, const unsigned short* __restrict__ th_lo,
    const unsigned short* __restrict__ ph_hi, const unsigned short* __restrict__ ph_lo,
    const unsigned short* __restrict__ gT, unsigned short* __restrict__ attn)
{
    extern __shared__ __align__(16) char smem[];
    const int tid   = threadIdx.x;
    const int wv    = tid >> 6;
    const int lane  = tid & 63;
    const int l15   = lane & 15;
    const int g     = lane >> 4;
    const int pband = wv & 3;      // 16-row q band
    const int q     = wv >> 2;     // KV parity 0..1

    const int bid = blockIdx.y * 64 + blockIdx.x;
    const int wg  = (bid & 7) * 32 + (bid >> 3);   // XCD-chunked, bijective
    const int qt  = wg & 63;
    const int bb  = wg >> 6;
    const int row0 = qt * 64;
    const size_t base = (size_t)bb * NN * NF;

    // Q fragments in registers (16 q-rows per wave)
    short8 qhi[2], qlo[2];
    {
        const size_t qr = base + (size_t)(row0 + pband*16 + l15) * NF + 8*g;
        qhi[0] = *reinterpret_cast<const short8*>(&th_hi[qr]);
        qhi[1] = *reinterpret_cast<const short8*>(&th_hi[qr + 32]);
        qlo[0] = *reinterpret_cast<const short8*>(&th_lo[qr]);
        qlo[1] = *reinterpret_cast<const short8*>(&th_lo[qr + 32]);
    }

    f32x4 o[4];
    #pragma unroll
    for (int ff = 0; ff < 4; ++ff) o[ff] = (f32x4){0.f,0.f,0.f,0.f};
    float m_run = -1e30f, l_run = 0.f;

    // staging geometry: wave wv stages 8-row chunk [wv*8, wv*8+8) of each of
    // the 6 planes (2 tiles x {khi,klo,vT}).  lane -> row wv*8+(lane>>3),
    // source col byte pre-swizzled so linear LDS == swizzled layout.
    const int srow = wv*8 + (lane >> 3);
    const int scol = ((lane & 7) ^ (lane >> 3)) << 4;
    char* psb = smem + 98304 + wv * 2048;
    const int swzP = (l15 & 7) << 4;

#define STAGE(tt, d) { \
    const int j0 = 2*(tt); \
    char* db = smem + (d)*49152 + wv*1024; \
    _Pragma("unroll") \
    for (int s = 0; s < 2; ++s) { \
        const size_t kb2 = base*2 + (size_t)((j0+s)*64 + srow) * 128 + scol; \
        gload16((const char*)ph_hi + kb2, db + s*24576); \
        gload16((const char*)ph_lo + kb2, db + s*24576 + 8192); \
        const size_t vb2 = ((size_t)(bb*NF + srow) * NN + (j0+s)*64) * 2 + scol; \
        gload16((const char*)gT + vb2, db + s*24576 + 16384); \
    } }

    STAGE(0, 0);
    __syncthreads();

    for (int t = 0; t < 32; ++t) {
        const int cur = t & 1;
        if (t < 31) STAGE(t + 1, cur ^ 1);

        const char* kb = smem + cur*49152 + q*24576;

        // ---- QK^T swapped: sacc[mi][reg] = S[kv=mi*16+4g+reg][qrow=l15]
        f32x4 sacc[4];
        #pragma unroll
        for (int mi = 0; mi < 4; ++mi) sacc[mi] = (f32x4){0.f,0.f,0.f,0.f};

        __builtin_amdgcn_s_setprio(1);
        #pragma unroll
        for (int ks = 0; ks < 2; ++ks) {
            short8 kh[4], kl[4];
            #pragma unroll
            for (int mi = 0; mi < 4; ++mi) {
                const int rr = mi*16 + l15;
                const char* rp = kb + rr*128;
                const int off = (ks*64 + g*16) ^ ((rr & 7) << 4);
                kh[mi] = *reinterpret_cast<const short8*>(rp + off);
                kl[mi] = *reinterpret_cast<const short8*>(rp + 8192 + off);
            }
            #pragma unroll
            for (int mi = 0; mi < 4; ++mi) {
                sacc[mi] = MFMA16(kh[mi], qhi[ks], sacc[mi]);
                sacc[mi] = MFMA16(kl[mi], qhi[ks], sacc[mi]);
                sacc[mi] = MFMA16(kh[mi], qlo[ks], sacc[mi]);
            }
        }
        __builtin_amdgcn_s_setprio(0);

        // ---- online softmax (one q-row per lane; reduce across g via shfl)
        {
            float mx = -1e30f;
            #pragma unroll
            for (int mi = 0; mi < 4; ++mi)
                #pragma unroll
                for (int rg = 0; rg < 4; ++rg) mx = fmaxf(mx, sacc[mi][rg]);
            mx = fmaxf(mx, __shfl_xor(mx, 16));
            mx = fmaxf(mx, __shfl_xor(mx, 32));
            const float mnew = fmaxf(m_run, mx);
            const float scl  = __expf(m_run - mnew);
            m_run = mnew;
            float ps = 0.f;
            uint2 w[4];
            #pragma unroll
            for (int mi = 0; mi < 4; ++mi) {
                float p0 = __expf(sacc[mi][0] - mnew);
                float p1 = __expf(sacc[mi][1] - mnew);
                float p2 = __expf(sacc[mi][2] - mnew);
                float p3 = __expf(sacc[mi][3] - mnew);
                ps += (p0 + p1) + (p2 + p3);
                w[mi].x = pkbf(p0, p1);
                w[mi].y = pkbf(p2, p3);
            }
            ps += __shfl_xor(ps, 16);
            ps += __shfl_xor(ps, 32);
            l_run = l_run * scl + ps;
            #pragma unroll
            for (int ff = 0; ff < 4; ++ff) o[ff] *= scl;
            char* prow = psb + l15 * 128;
            #pragma unroll
            for (int mi = 0; mi < 4; ++mi)
                *reinterpret_cast<uint2*>(prow + ((mi*32 + 8*g) ^ swzP)) = w[mi];
        }
        asm volatile("s_waitcnt lgkmcnt(0)" ::: "memory");
        __builtin_amdgcn_sched_barrier(0);

        // ---- PV: o[ff][reg] = O[f=ff*16+4g+reg][qrow=l15]
        __builtin_amdgcn_s_setprio(1);
        const char* vb = kb + 16384;
        #pragma unroll
        for (int ks = 0; ks < 2; ++ks) {
            short8 pfr = *reinterpret_cast<const short8*>(
                psb + l15*128 + ((ks*64 + 16*g) ^ swzP));
            #pragma unroll
            for (int ff = 0; ff < 4; ++ff) {
                const int fr = ff*16 + l15;
                short8 va = *reinterpret_cast<const short8*>(
                    vb + fr*128 + ((ks*64 + g*16) ^ ((fr & 7) << 4)));
                o[ff] = MFMA16(va, pfr, o[ff]);
            }
        }
        __builtin_amdgcn_s_setprio(0);

        __syncthreads();
    }

    // ---- 2-way split-K merge
    float* mO = (float*)smem;                // [4 band][16][64] f32 = 16 KB
    float* ml = (float*)(smem + 16384);      // [64][2]
    if (q == 1) {
        float* bo2 = mO + pband * 1024;
        #pragma unroll
        for (int ff = 0; ff < 4; ++ff)
            *reinterpret_cast<f32x4*>(&bo2[l15*64 + ff*16 + 4*g]) = o[ff];
        if (g == 0) {
            ml[(pband*16 + l15)*2 + 0] = m_run;
            ml[(pband*16 + l15)*2 + 1] = l_run;
        }
    }
    __syncthreads();
    if (q == 0) {
        const float m1 = ml[(pband*16 + l15)*2 + 0];
        const float l1 = ml[(pband*16 + l15)*2 + 1];
        const float m  = fmaxf(m_run, m1);
        const float a0 = __expf(m_run - m);
        const float a1 = __expf(m1 - m);
        const float inv = 1.0f / (a0 * l_run + a1 * l1);
        #pragma unroll
        for (int ff = 0; ff < 4; ++ff) {
            const float* bo2 = mO + pband*1024 + l15*64 + ff*16 + 4*g;
            float4 v = *reinterpret_cast<const float4*>(bo2);
            ushort4 st;
            st.x = f2bf((a0*o[ff][0] + a1*v.x) * inv);
            st.y = f2bf((a0*o[ff][1] + a1*v.y) * inv);
            st.z = f2bf((a0*o[ff][2] + a1*v.z) * inv);
            st.w = f2bf((a0*o[ff][3] + a1*v.w) * inv);
            *reinterpret_cast<ushort4*>(
                &attn[base + (size_t)(row0 + pband*16 + l15)*NF + ff*16 + 4*g]) = st;
        }
    }
#undef STAGE
}

// ---------------------------------------------------------------------------
// Kernel 3: out = x + attn(bf16) @ WoT(bf16) + b (unchanged from round 5).
// ---------------------------------------------------------------------------
__global__ __launch_bounds__(256) void outproj_kernel(
    const unsigned short* __restrict__ attn, const unsigned short* __restrict__ wo_t,
    const float* __restrict__ bo, const float* __restrict__ x, float* __restrict__ out)
{
    const int tid  = threadIdx.x;
    const int wv   = tid >> 6;
    const int lane = tid & 63;
    const int l15  = lane & 15;
    const int g    = lane >> 4;
    const int row0 = blockIdx.x * 32;

    short8 af[2][2];
    #pragma unroll
    for (int mi = 0; mi < 2; ++mi)
        #pragma unroll
        for (int ks = 0; ks < 2; ++ks)
            af[mi][ks] = *reinterpret_cast<const short8*>(
                &attn[(size_t)(row0 + 16*mi + l15) * NF + ks*32 + 8*g]);

    f32x4 acc[2][8];
    #pragma unroll
    for (int mi = 0; mi < 2; ++mi)
        #pragma unroll
        for (int nf = 0; nf < 8; ++nf) acc[mi][nf] = (f32x4){0.f,0.f,0.f,0.f};

    #pragma unroll
    for (int nf = 0; nf < 8; ++nf) {
        const int c = wv*128 + nf*16 + l15;
        #pragma unroll
        for (int ks = 0; ks < 2; ++ks) {
            short8 wf = *reinterpret_cast<const short8*>(&wo_t[(size_t)c * NF + ks*32 + 8*g]);
            acc[0][nf] = MFMA16(af[0][ks], wf, acc[0][nf]);
            acc[1][nf] = MFMA16(af[1][ks], wf, acc[1][nf]);
        }
    }

    float bov[8];
    #pragma unroll
    for (int nf = 0; nf < 8; ++nf) bov[nf] = bo[wv*128 + nf*16 + l15];

    #pragma unroll
    for (int mi = 0; mi < 2; ++mi)
        #pragma unroll
        for (int reg = 0; reg < 4; ++reg) {
            const int m = row0 + 16*mi + 4*g + reg;
            #pragma unroll
            for (int nf = 0; nf < 8; ++nf) {
                const size_t idx = (size_t)m * NC + wv*128 + nf*16 + l15;
                out[idx] = acc[mi][nf][reg] + bov[nf] + x[idx];
            }
        }
}

// ---------------------------------------------------------------------------
extern "C" void kernel_launch(void* const* d_in, const int* in_sizes, int n_in,
                              void* d_out, int out_size, void* d_ws, size_t ws_size,
                              hipStream_t stream) {
    const float* x  = (const float*)d_in[0];
    const float* Wt = (const float*)d_in[1];
    const float* bt = (const float*)d_in[2];
    const float* Wp = (const float*)d_in[3];
    const float* bp = (const float*)d_in[4];
    const float* Wg = (const float*)d_in[5];
    const float* bg = (const float*)d_in[6];
    const float* Wo = (const float*)d_in[7];
    const float* bo = (const float*)d_in[8];
    float* out = (float*)d_out;

    const size_t per = (size_t)NB * NN * NF;   // 1,048,576
    unsigned short* th_hi = (unsigned short*)d_ws;
    unsigned short* th_lo = th_hi + per;
    unsigned short* ph_hi = th_lo + per;
    unsigned short* ph_lo = ph_hi + per;
    unsigned short* gTw   = ph_lo + per;
    unsigned short* at_bf = gTw + per;
    unsigned short* wt_hi = at_bf + per;
    unsigned short* wt_lo = wt_hi + 192 * NC;
    unsigned short* wo_t  = wt_lo + 192 * NC;

    hipFuncSetAttribute(reinterpret_cast<const void*>(flash_kernel),
                        hipFuncAttributeMaxDynamicSharedMemorySize, 131072);

    const int M = NB * NN;  // 16384

    prep_kernel<<<128, 256, 0, stream>>>(Wt, Wp, Wg, Wo, wt_hi, wt_lo, wo_t);
    proj_kernel<<<M / 32, 256, 0, stream>>>(
        x, wt_hi, wt_lo, bt, bp, bg, th_hi, th_lo, ph_hi, ph_lo, gTw);
    flash_kernel<<<dim3(64, 4), 512, 131072, stream>>>(
        th_hi, th_lo, ph_hi, ph_lo, gTw, at_bf);
    outproj_kernel<<<M / 32, 256, 0, stream>>>(at_bf, wo_t, bo, x, out);
}

// Round 7
// 201.354 us; speedup vs baseline: 1.3617x; 1.0093x over previous
//
#include <hip/hip_runtime.h>
#include <math.h>

#define NB 4
#define NN 4096
#define NC 512
#define NF 64

typedef __attribute__((ext_vector_type(8))) short short8;
typedef __attribute__((ext_vector_type(4))) float f32x4;

#define MFMA16(a,b,c) __builtin_amdgcn_mfma_f32_16x16x32_bf16(a,b,c,0,0,0)

static __device__ inline unsigned short f2bf(float f) {
    unsigned u = __float_as_uint(f);
    u = (u + 0x7FFFu + ((u >> 16) & 1u)) >> 16;
    return (unsigned short)u;
}
static __device__ inline float bf2f(unsigned short h) {
    return __uint_as_float(((unsigned)h) << 16);
}
// HW packed f32->bf16 (RTNE on gfx950); lo half = first operand
static __device__ __forceinline__ unsigned cvtpk(float lo, float hi) {
    unsigned r;
    asm("v_cvt_pk_bf16_f32 %0, %1, %2" : "=v"(r) : "v"(lo), "v"(hi));
    return r;
}
union U8 { unsigned short u[8]; short8 v; };
union U32x4 { unsigned u[4]; short8 v; };

// global -> LDS async DMA, 16B per lane; LDS dest wave-uniform base.
static __device__ __forceinline__ void gload16(const void* gsrc, void* ldst) {
    __builtin_amdgcn_global_load_lds(
        (const __attribute__((address_space(1))) unsigned int*)gsrc,
        (__attribute__((address_space(3))) unsigned int*)ldst,
        16, 0, 0);
}

// ---------------------------------------------------------------------------
// Kernel 0: weight prep (unchanged).
// ---------------------------------------------------------------------------
__global__ __launch_bounds__(256) void prep_kernel(
    const float* __restrict__ Wt, const float* __restrict__ Wp,
    const float* __restrict__ Wg, const float* __restrict__ Wo,
    unsigned short* __restrict__ wt_hi, unsigned short* __restrict__ wt_lo,
    unsigned short* __restrict__ wo_t)
{
    const int idx = blockIdx.x * 256 + threadIdx.x;
    if (blockIdx.x < 96) {
        const int c  = idx >> 7;
        const int k0 = (idx & 127) << 2;
        const float* W = (c < 64) ? Wt : (c < 128) ? Wp : Wg;
        const int cc = c & 63;
        #pragma unroll
        for (int j = 0; j < 4; ++j) {
            float v = W[(size_t)(k0 + j) * NF + cc];
            unsigned short h = f2bf(v);
            wt_hi[c * NC + k0 + j] = h;
            wt_lo[c * NC + k0 + j] = f2bf(v - bf2f(h));
        }
    } else {
        const int i2 = idx - 96 * 256;
        const int c  = i2 >> 4;
        const int f0 = (i2 & 15) << 2;
        #pragma unroll
        for (int j = 0; j < 4; ++j)
            wo_t[c * NF + f0 + j] = f2bf(Wo[(size_t)(f0 + j) * NC + c]);
    }
}

// ---------------------------------------------------------------------------
// Kernel 1: projections via bf16x2-split MFMA; x-split now uses HW cvt_pk.
// ---------------------------------------------------------------------------
__global__ __launch_bounds__(256) void proj_kernel(
    const float* __restrict__ x,
    const unsigned short* __restrict__ wt_hi, const unsigned short* __restrict__ wt_lo,
    const float* __restrict__ bt, const float* __restrict__ bp, const float* __restrict__ bg,
    unsigned short* __restrict__ th_hi, unsigned short* __restrict__ th_lo,
    unsigned short* __restrict__ ph_hi, unsigned short* __restrict__ ph_lo,
    unsigned short* __restrict__ gT)
{
    __shared__ unsigned short gtr[4][32][16];
    const int tid  = threadIdx.x;
    const int wv   = tid >> 6;
    const int lane = tid & 63;
    const int l15  = lane & 15;
    const int g    = lane >> 4;
    const int row0 = blockIdx.x * 32;

    f32x4 acc[2][3];
    #pragma unroll
    for (int mi = 0; mi < 2; ++mi)
        #pragma unroll
        for (int nf = 0; nf < 3; ++nf) acc[mi][nf] = (f32x4){0.f,0.f,0.f,0.f};

    for (int k0 = 0; k0 < NC; k0 += 32) {
        short8 xhi[2], xlo[2];
        #pragma unroll
        for (int mi = 0; mi < 2; ++mi) {
            const float* xp = &x[(size_t)(row0 + 16*mi + l15) * NC + k0 + 8*g];
            float4 a = *reinterpret_cast<const float4*>(xp);
            float4 b = *reinterpret_cast<const float4*>(xp + 4);
            unsigned h0 = cvtpk(a.x, a.y), h1 = cvtpk(a.z, a.w);
            unsigned h2 = cvtpk(b.x, b.y), h3 = cvtpk(b.z, b.w);
            float l0 = a.x - __uint_as_float(h0 << 16);
            float l1 = a.y - __uint_as_float(h0 & 0xFFFF0000u);
            float l2 = a.z - __uint_as_float(h1 << 16);
            float l3 = a.w - __uint_as_float(h1 & 0xFFFF0000u);
            float l4 = b.x - __uint_as_float(h2 << 16);
            float l5 = b.y - __uint_as_float(h2 & 0xFFFF0000u);
            float l6 = b.z - __uint_as_float(h3 << 16);
            float l7 = b.w - __uint_as_float(h3 & 0xFFFF0000u);
            U32x4 H; H.u[0]=h0; H.u[1]=h1; H.u[2]=h2; H.u[3]=h3;
            U32x4 L; L.u[0]=cvtpk(l0,l1); L.u[1]=cvtpk(l2,l3);
                     L.u[2]=cvtpk(l4,l5); L.u[3]=cvtpk(l6,l7);
            xhi[mi] = H.v; xlo[mi] = L.v;
        }
        #pragma unroll
        for (int nf = 0; nf < 3; ++nf) {
            const int c = (wv + 4*nf) * 16 + l15;
            short8 wh = *reinterpret_cast<const short8*>(&wt_hi[(size_t)c * NC + k0 + 8*g]);
            short8 wl = *reinterpret_cast<const short8*>(&wt_lo[(size_t)c * NC + k0 + 8*g]);
            #pragma unroll
            for (int mi = 0; mi < 2; ++mi) {
                acc[mi][nf] = MFMA16(xhi[mi], wh, acc[mi][nf]);
                acc[mi][nf] = MFMA16(xlo[mi], wh, acc[mi][nf]);
                acc[mi][nf] = MFMA16(xhi[mi], wl, acc[mi][nf]);
            }
        }
    }

    #pragma unroll
    for (int nf = 0; nf < 2; ++nf) {
        unsigned short* hi_arr = nf ? ph_hi : th_hi;
        unsigned short* lo_arr = nf ? ph_lo : th_lo;
        const float bb = (nf ? bp : bt)[wv*16 + l15];
        #pragma unroll
        for (int mi = 0; mi < 2; ++mi)
            #pragma unroll
            for (int reg = 0; reg < 4; ++reg) {
                const int m = row0 + 16*mi + 4*g + reg;
                float v = acc[mi][nf][reg] + bb;
                unsigned short h = f2bf(v);
                hi_arr[(size_t)m * NF + wv*16 + l15] = h;
                lo_arr[(size_t)m * NF + wv*16 + l15] = f2bf(v - bf2f(h));
            }
    }
    {
        const float bb = bg[wv*16 + l15];
        #pragma unroll
        for (int mi = 0; mi < 2; ++mi)
            #pragma unroll
            for (int reg = 0; reg < 4; ++reg)
                gtr[wv][16*mi + 4*g + reg][l15] = f2bf(acc[mi][2][reg] + bb);
        asm volatile("s_waitcnt lgkmcnt(0)" ::: "memory");
        U8 pkt;
        #pragma unroll
        for (int j = 0; j < 8; ++j) pkt.u[j] = gtr[wv][8*g + j][l15];
        const int bbi = row0 >> 12;
        const int nbase = row0 & (NN - 1);
        *reinterpret_cast<short8*>(
            &gT[(size_t)(bbi*NF + wv*16 + l15) * NN + nbase + 8*g]) = pkt.v;
    }
}

// ---------------------------------------------------------------------------
// Kernel 2: flash attention v5. 1024 thr (16 waves) = 4 bands x 4 KV parity.
// Single-buffered 4-tile set staged via global_load_lds (pre-swizzled src);
// all LDS read addresses loop-invariant (hoisted); HW cvt_pk P packing;
// 4-way split-K merge. Dyn LDS 128KB: slots q*24576 {khi,klo,vT} + P 98304+.
// ---------------------------------------------------------------------------
__global__ __launch_bounds__(1024, 4) void flash_kernel(
    const unsigned short* __restrict__ th_hi, const unsigned short* __restrict__ th_lo,
    const unsigned short* __restrict__ ph_hi, const unsigned short* __restrict__ ph_lo,
    const unsigned short* __restrict__ gT, unsigned short* __restrict__ attn)
{
    extern __shared__ __align__(16) char smem[];
    const int tid   = threadIdx.x;
    const int wv    = tid >> 6;       // 0..15
    const int lane  = tid & 63;
    const int l15   = lane & 15;
    const int g     = lane >> 4;
    const int pband = wv & 3;         // 16-row q band
    const int q     = wv >> 2;        // KV parity 0..3

    const int bid = blockIdx.y * 64 + blockIdx.x;
    const int wg  = (bid & 7) * 32 + (bid >> 3);   // XCD-chunked, bijective
    const int qt  = wg & 63;
    const int bb  = wg >> 6;
    const int row0 = qt * 64;
    const size_t base = (size_t)bb * NN * NF;

    // Q fragments in registers
    short8 qhi[2], qlo[2];
    {
        const size_t qr = base + (size_t)(row0 + pband*16 + l15) * NF + 8*g;
        qhi[0] = *reinterpret_cast<const short8*>(&th_hi[qr]);
        qhi[1] = *reinterpret_cast<const short8*>(&th_hi[qr + 32]);
        qlo[0] = *reinterpret_cast<const short8*>(&th_lo[qr]);
        qlo[1] = *reinterpret_cast<const short8*>(&th_lo[qr + 32]);
    }

    f32x4 o[4];
    #pragma unroll
    for (int ff = 0; ff < 4; ++ff) o[ff] = (f32x4){0.f,0.f,0.f,0.f};
    float m_run = -1e30f, l_run = 0.f;

    // ---- hoisted, loop-invariant LDS read/write addresses ----
    const int swz = (l15 & 7) << 4;
    const char* kb = smem + q * 24576;
    const char* aK[2][4];
    #pragma unroll
    for (int ks = 0; ks < 2; ++ks)
        #pragma unroll
        for (int mi = 0; mi < 4; ++mi)
            aK[ks][mi] = kb + (mi*16 + l15)*128 + ((ks*64 + g*16) ^ swz);
    char* psb = smem + 98304 + wv * 2048;
    const char* aP[2];
    #pragma unroll
    for (int ks = 0; ks < 2; ++ks) aP[ks] = psb + l15*128 + ((ks*64 + g*16) ^ swz);
    char* wP[4];
    #pragma unroll
    for (int mi = 0; mi < 4; ++mi) wP[mi] = psb + l15*128 + ((mi*32 + 8*g) ^ swz);

    // ---- staging: waves 0..11, one plane each (slot sslot, kind) ----
    const int sslot = wv / 3;
    const int kind  = wv - sslot * 3;
    const int rl    = lane >> 3;
    const int scol  = ((lane & 7) ^ rl) << 4;   // inverse-swizzled source col
    char* ldst0 = smem + sslot*24576 + kind*8192;
    const char* gp;
    if (kind == 0)      gp = (const char*)ph_hi + base*2 + (size_t)(sslot*64 + rl)*128 + scol;
    else if (kind == 1) gp = (const char*)ph_lo + base*2 + (size_t)(sslot*64 + rl)*128 + scol;
    else                gp = (const char*)gT + ((size_t)(bb*NF + rl) * NN)*2 + sslot*128 + scol;

#define STAGE() \
    if (wv < 12) { \
        if (kind == 2) { \
            _Pragma("unroll") \
            for (int u = 0; u < 8; ++u) gload16(gp + (size_t)u*65536, ldst0 + u*1024); \
            gp += 512; \
        } else { \
            _Pragma("unroll") \
            for (int u = 0; u < 8; ++u) gload16(gp + u*1024, ldst0 + u*1024); \
            gp += 32768; \
        } \
    }

    STAGE();
    __syncthreads();

    for (int t = 0; t < 16; ++t) {
        // ---- QK^T swapped: sacc[mi][reg] = S[kv=mi*16+4g+reg][qrow=l15]
        f32x4 sacc[4];
        #pragma unroll
        for (int mi = 0; mi < 4; ++mi) sacc[mi] = (f32x4){0.f,0.f,0.f,0.f};

        __builtin_amdgcn_s_setprio(1);
        #pragma unroll
        for (int ks = 0; ks < 2; ++ks)
            #pragma unroll
            for (int mi = 0; mi < 4; ++mi) {
                short8 kh = *reinterpret_cast<const short8*>(aK[ks][mi]);
                short8 kl = *reinterpret_cast<const short8*>(aK[ks][mi] + 8192);
                sacc[mi] = MFMA16(kh, qhi[ks], sacc[mi]);
                sacc[mi] = MFMA16(kl, qhi[ks], sacc[mi]);
                sacc[mi] = MFMA16(kh, qlo[ks], sacc[mi]);
            }
        __builtin_amdgcn_s_setprio(0);

        // ---- online softmax (one q-row per lane; reduce across g via shfl)
        {
            float mx = -1e30f;
            #pragma unroll
            for (int mi = 0; mi < 4; ++mi)
                #pragma unroll
                for (int rg = 0; rg < 4; ++rg) mx = fmaxf(mx, sacc[mi][rg]);
            mx = fmaxf(mx, __shfl_xor(mx, 16));
            mx = fmaxf(mx, __shfl_xor(mx, 32));
            const float mnew = fmaxf(m_run, mx);
            const float scl  = __expf(m_run - mnew);
            m_run = mnew;
            float ps = 0.f;
            uint2 w[4];
            #pragma unroll
            for (int mi = 0; mi < 4; ++mi) {
                float p0 = __expf(sacc[mi][0] - mnew);
                float p1 = __expf(sacc[mi][1] - mnew);
                float p2 = __expf(sacc[mi][2] - mnew);
                float p3 = __expf(sacc[mi][3] - mnew);
                ps += (p0 + p1) + (p2 + p3);
                w[mi].x = cvtpk(p0, p1);
                w[mi].y = cvtpk(p2, p3);
            }
            ps += __shfl_xor(ps, 16);
            ps += __shfl_xor(ps, 32);
            l_run = l_run * scl + ps;
            #pragma unroll
            for (int ff = 0; ff < 4; ++ff) o[ff] *= scl;
            #pragma unroll
            for (int mi = 0; mi < 4; ++mi)
                *reinterpret_cast<uint2*>(wP[mi]) = w[mi];
        }
        asm volatile("s_waitcnt lgkmcnt(0)" ::: "memory");
        __builtin_amdgcn_sched_barrier(0);

        // ---- PV: o[ff][reg] = O[f=ff*16+4g+reg][qrow=l15]
        __builtin_amdgcn_s_setprio(1);
        #pragma unroll
        for (int ks = 0; ks < 2; ++ks) {
            short8 pfr = *reinterpret_cast<const short8*>(aP[ks]);
            #pragma unroll
            for (int ff = 0; ff < 4; ++ff) {
                short8 va = *reinterpret_cast<const short8*>(aK[ks][ff] + 16384);
                o[ff] = MFMA16(va, pfr, o[ff]);
            }
        }
        __builtin_amdgcn_s_setprio(0);

        __syncthreads();
        if (t < 15) { STAGE(); __syncthreads(); }
    }

    // ---- 4-way split-K merge (reuses staging LDS)
    float* mO = (float*)smem;                 // 12 x [16][64] f32 = 48 KB
    float* ml = (float*)(smem + 49152);       // [64][3][2]
    if (q > 0) {
        float* bo2 = mO + ((q - 1)*4 + pband) * 1024;
        #pragma unroll
        for (int ff = 0; ff < 4; ++ff)
            *reinterpret_cast<f32x4*>(&bo2[l15*64 + ff*16 + 4*g]) = o[ff];
        if (g == 0) {
            const int rg = pband*16 + l15;
            ml[rg*6 + (q-1)*2 + 0] = m_run;
            ml[rg*6 + (q-1)*2 + 1] = l_run;
        }
    }
    __syncthreads();
    if (q == 0) {
        const int rg = pband*16 + l15;
        float m = m_run;
        float mi_[3], li_[3];
        #pragma unroll
        for (int i = 0; i < 3; ++i) {
            mi_[i] = ml[rg*6 + i*2 + 0];
            li_[i] = ml[rg*6 + i*2 + 1];
            m = fmaxf(m, mi_[i]);
        }
        const float a0 = __expf(m_run - m);
        float L = a0 * l_run;
        float ai[3];
        #pragma unroll
        for (int i = 0; i < 3; ++i) { ai[i] = __expf(mi_[i] - m); L += ai[i]*li_[i]; }
        const float inv = 1.0f / L;
        #pragma unroll
        for (int ff = 0; ff < 4; ++ff) {
            f32x4 a = o[ff] * a0;
            #pragma unroll
            for (int i = 0; i < 3; ++i) {
                const float* bo2 = mO + (i*4 + pband)*1024 + l15*64 + ff*16 + 4*g;
                float4 v = *reinterpret_cast<const float4*>(bo2);
                a[0] += ai[i]*v.x; a[1] += ai[i]*v.y;
                a[2] += ai[i]*v.z; a[3] += ai[i]*v.w;
            }
            ushort4 st;
            st.x = f2bf(a[0]*inv); st.y = f2bf(a[1]*inv);
            st.z = f2bf(a[2]*inv); st.w = f2bf(a[3]*inv);
            *reinterpret_cast<ushort4*>(
                &attn[base + (size_t)(row0 + pband*16 + l15)*NF + ff*16 + 4*g]) = st;
        }
    }
#undef STAGE
}

// ---------------------------------------------------------------------------
// Kernel 3: out = x + attn(bf16) @ WoT(bf16) + b (unchanged).
// ---------------------------------------------------------------------------
__global__ __launch_bounds__(256) void outproj_kernel(
    const unsigned short* __restrict__ attn, const unsigned short* __restrict__ wo_t,
    const float* __restrict__ bo, const float* __restrict__ x, float* __restrict__ out)
{
    const int tid  = threadIdx.x;
    const int wv   = tid >> 6;
    const int lane = tid & 63;
    const int l15  = lane & 15;
    const int g    = lane >> 4;
    const int row0 = blockIdx.x * 32;

    short8 af[2][2];
    #pragma unroll
    for (int mi = 0; mi < 2; ++mi)
        #pragma unroll
        for (int ks = 0; ks < 2; ++ks)
            af[mi][ks] = *reinterpret_cast<const short8*>(
                &attn[(size_t)(row0 + 16*mi + l15) * NF + ks*32 + 8*g]);

    f32x4 acc[2][8];
    #pragma unroll
    for (int mi = 0; mi < 2; ++mi)
        #pragma unroll
        for (int nf = 0; nf < 8; ++nf) acc[mi][nf] = (f32x4){0.f,0.f,0.f,0.f};

    #pragma unroll
    for (int nf = 0; nf < 8; ++nf) {
        const int c = wv*128 + nf*16 + l15;
        #pragma unroll
        for (int ks = 0; ks < 2; ++ks) {
            short8 wf = *reinterpret_cast<const short8*>(&wo_t[(size_t)c * NF + ks*32 + 8*g]);
            acc[0][nf] = MFMA16(af[0][ks], wf, acc[0][nf]);
            acc[1][nf] = MFMA16(af[1][ks], wf, acc[1][nf]);
        }
    }

    float bov[8];
    #pragma unroll
    for (int nf = 0; nf < 8; ++nf) bov[nf] = bo[wv*128 + nf*16 + l15];

    #pragma unroll
    for (int mi = 0; mi < 2; ++mi)
        #pragma unroll
        for (int reg = 0; reg < 4; ++reg) {
            const int m = row0 + 16*mi + 4*g + reg;
            #pragma unroll
            for (int nf = 0; nf < 8; ++nf) {
                const size_t idx = (size_t)m * NC + wv*128 + nf*16 + l15;
                out[idx] = acc[mi][nf][reg] + bov[nf] + x[idx];
            }
        }
}

// ---------------------------------------------------------------------------
extern "C" void kernel_launch(void* const* d_in, const int* in_sizes, int n_in,
                              void* d_out, int out_size, void* d_ws, size_t ws_size,
                              hipStream_t stream) {
    const float* x  = (const float*)d_in[0];
    const float* Wt = (const float*)d_in[1];
    const float* bt = (const float*)d_in[2];
    const float* Wp = (const float*)d_in[3];
    const float* bp = (const float*)d_in[4];
    const float* Wg = (const float*)d_in[5];
    const float* bg = (const float*)d_in[6];
    const float* Wo = (const float*)d_in[7];
    const float* bo = (const float*)d_in[8];
    float* out = (float*)d_out;

    const size_t per = (size_t)NB * NN * NF;   // 1,048,576
    unsigned short* th_hi = (unsigned short*)d_ws;
    unsigned short* th_lo = th_hi + per;
    unsigned short* ph_hi = th_lo + per;
    unsigned short* ph_lo = ph_hi + per;
    unsigned short* gTw   = ph_lo + per;
    unsigned short* at_bf = gTw + per;
    unsigned short* wt_hi = at_bf + per;
    unsigned short* wt_lo = wt_hi + 192 * NC;
    unsigned short* wo_t  = wt_lo + 192 * NC;

    hipFuncSetAttribute(reinterpret_cast<const void*>(flash_kernel),
                        hipFuncAttributeMaxDynamicSharedMemorySize, 131072);

    const int M = NB * NN;  // 16384

    prep_kernel<<<128, 256, 0, stream>>>(Wt, Wp, Wg, Wo, wt_hi, wt_lo, wo_t);
    proj_kernel<<<M / 32, 256, 0, stream>>>(
        x, wt_hi, wt_lo, bt, bp, bg, th_hi, th_lo, ph_hi, ph_lo, gTw);
    flash_kernel<<<dim3(64, 4), 1024, 131072, stream>>>(
        th_hi, th_lo, ph_hi, ph_lo, gTw, at_bf);
    outproj_kernel<<<M / 32, 256, 0, stream>>>(at_bf, wo_t, bo, x, out);
}